// Round 1
// baseline (345.335 us; speedup 1.0000x reference)
//
#include <hip/hip_runtime.h>
#include <math.h>

#define N_ROWS 8192
#define N_COLS 32768
#define K_TOP 10
#define STEP_W 0.1f
#define THREADS 256

// Insert (v,i) into the descending sorted register lists tv/ti.
// Caller guarantees the scan visits strictly increasing column indices, so a
// strict '>' everywhere implements jax.lax.top_k's lower-index-wins tie rule.
#define TRY_INSERT(v, i)                                                      \
  do {                                                                        \
    if ((v) > tv[K_TOP - 1]) {                                                \
      tv[K_TOP - 1] = (v);                                                    \
      ti[K_TOP - 1] = (i);                                                    \
      _Pragma("unroll") for (int _j = K_TOP - 1; _j >= 1; --_j) {             \
        if (tv[_j] > tv[_j - 1]) {                                            \
          float _tv = tv[_j]; tv[_j] = tv[_j - 1]; tv[_j - 1] = _tv;          \
          int   _ti = ti[_j]; ti[_j] = ti[_j - 1]; ti[_j - 1] = _ti;          \
        }                                                                     \
      }                                                                       \
    }                                                                         \
  } while (0)

__global__ __launch_bounds__(THREADS) void topk_rows_kernel(
    const float* __restrict__ inp, const float* __restrict__ target,
    float* __restrict__ row_err) {
  const int row = blockIdx.x;
  const int tid = threadIdx.x;

  float tv[K_TOP];
  int ti[K_TOP];
#pragma unroll
  for (int j = 0; j < K_TOP; ++j) {
    tv[j] = -INFINITY;
    ti[j] = 0x7FFFFFFF;
  }

  // --- streaming scan: coalesced float4, 32768 cols = 8192 float4s ---
  const float4* rp4 =
      reinterpret_cast<const float4*>(inp + (size_t)row * N_COLS);
  constexpr int ITERS = N_COLS / 4 / THREADS;  // 32
#pragma unroll 2
  for (int it = 0; it < ITERS; ++it) {
    const int v4 = it * THREADS + tid;
    const float4 d = rp4[v4];
    const int c0 = v4 * 4;
    const float m = fmaxf(fmaxf(d.x, d.y), fmaxf(d.z, d.w));
    if (m > tv[K_TOP - 1]) {  // quick reject for the whole quad
      TRY_INSERT(d.x, c0 + 0);
      TRY_INSERT(d.y, c0 + 1);
      TRY_INSERT(d.z, c0 + 2);
      TRY_INSERT(d.w, c0 + 3);
    }
  }

  // --- block-level merge: extract global top-10 of 256 sorted lists ---
  __shared__ float sv[THREADS / 64];
  __shared__ int si[THREADS / 64];
  const int lane = tid & 63;
  const int wid = tid >> 6;

  float myv = tv[0];
  int myi = ti[0];
  float pred = 0.0f;

  for (int k = 0; k < K_TOP; ++k) {
    // wave argmax over 64 lanes ((v,i) pairs are unique per column owner)
    float v = myv;
    int i = myi;
#pragma unroll
    for (int off = 32; off >= 1; off >>= 1) {
      const float ov = __shfl_xor(v, off, 64);
      const int oi = __shfl_xor(i, off, 64);
      if (ov > v || (ov == v && oi < i)) {
        v = ov;
        i = oi;
      }
    }
    if (lane == 0) {
      sv[wid] = v;
      si[wid] = i;
    }
    __syncthreads();
    float wv = sv[0];
    int wi = si[0];
#pragma unroll
    for (int w = 1; w < THREADS / 64; ++w) {
      const float ov = sv[w];
      const int oi = si[w];
      if (ov > wv || (ov == wv && oi < wi)) {
        wv = ov;
        wi = oi;
      }
    }
    __syncthreads();  // protect sv/si before next iteration overwrites

    pred += wv * ((float)wi * STEP_W + 1.0f);

    if (myv == wv && myi == wi) {
      // pop my head: static unrolled shift keeps everything in registers
#pragma unroll
      for (int j = 0; j < K_TOP - 1; ++j) {
        tv[j] = tv[j + 1];
        ti[j] = ti[j + 1];
      }
      tv[K_TOP - 1] = -INFINITY;
      ti[K_TOP - 1] = 0x7FFFFFFF;
      myv = tv[0];
      myi = ti[0];
    }
  }

  if (tid == 0) {
    const float e = target[row] - pred;
    row_err[row] = e * e;
  }
}

__global__ __launch_bounds__(THREADS) void reduce_mean_kernel(
    const float* __restrict__ row_err, float* __restrict__ out) {
  const int tid = threadIdx.x;
  float s = 0.0f;
#pragma unroll
  for (int i = tid; i < N_ROWS; i += THREADS) s += row_err[i];
#pragma unroll
  for (int off = 32; off >= 1; off >>= 1) s += __shfl_xor(s, off, 64);
  __shared__ float sw[THREADS / 64];
  const int lane = tid & 63;
  const int wid = tid >> 6;
  if (lane == 0) sw[wid] = s;
  __syncthreads();
  if (tid == 0) {
    float t = 0.0f;
#pragma unroll
    for (int w = 0; w < THREADS / 64; ++w) t += sw[w];
    out[0] = t / (float)N_ROWS;
  }
}

extern "C" void kernel_launch(void* const* d_in, const int* in_sizes, int n_in,
                              void* d_out, int out_size, void* d_ws,
                              size_t ws_size, hipStream_t stream) {
  const float* inp = (const float*)d_in[0];     // [8192, 32768] f32
  const float* target = (const float*)d_in[1];  // [8192] f32
  float* row_err = (float*)d_ws;                // 8192 f32 scratch
  float* out = (float*)d_out;                   // scalar f32

  topk_rows_kernel<<<N_ROWS, THREADS, 0, stream>>>(inp, target, row_err);
  reduce_mean_kernel<<<1, THREADS, 0, stream>>>(row_err, out);
}

// Round 2
// 275.091 us; speedup vs baseline: 1.2553x; 1.2553x over previous
//
#include <hip/hip_runtime.h>
#include <math.h>

#define N_ROWS 8192
#define N_COLS 32768
#define K_TOP 10
#define STEP_W 0.1f
#define THREADS 256
#define CAP 2048
#define BOOT_ITERS 4
#define TOTAL_ITERS (N_COLS / 4 / THREADS)  // 32

// Insert (v,i) into descending sorted register lists tv/ti. Strict '>' :
// with in-scan-order arrival, equal values keep the earlier (lower) index,
// matching jax.lax.top_k.
#define TRY_INSERT(v, i)                                                      \
  do {                                                                        \
    if ((v) > tv[K_TOP - 1]) {                                                \
      tv[K_TOP - 1] = (v);                                                    \
      ti[K_TOP - 1] = (i);                                                    \
      _Pragma("unroll") for (int _j = K_TOP - 1; _j >= 1; --_j) {             \
        if (tv[_j] > tv[_j - 1]) {                                            \
          float _tv = tv[_j]; tv[_j] = tv[_j - 1]; tv[_j - 1] = _tv;          \
          int   _ti = ti[_j]; ti[_j] = ti[_j - 1]; ti[_j - 1] = _ti;          \
        }                                                                     \
      }                                                                       \
    }                                                                         \
  } while (0)

// Tiebreak-aware insert for candidates arriving in arbitrary (atomic) order:
// total order is (value desc, index asc).
#define TRY_INSERT_TB(v, i)                                                   \
  do {                                                                        \
    if ((v) > tv[K_TOP - 1] ||                                                \
        ((v) == tv[K_TOP - 1] && (i) < ti[K_TOP - 1])) {                      \
      tv[K_TOP - 1] = (v);                                                    \
      ti[K_TOP - 1] = (i);                                                    \
      _Pragma("unroll") for (int _j = K_TOP - 1; _j >= 1; --_j) {             \
        if (tv[_j] > tv[_j - 1] ||                                            \
            (tv[_j] == tv[_j - 1] && ti[_j] < ti[_j - 1])) {                  \
          float _tv = tv[_j]; tv[_j] = tv[_j - 1]; tv[_j - 1] = _tv;          \
          int   _ti = ti[_j]; ti[_j] = ti[_j - 1]; ti[_j - 1] = _ti;          \
        }                                                                     \
      }                                                                       \
    }                                                                         \
  } while (0)

// 10 rounds of block-wide argmax over the heads of per-lane sorted lists
// (k-way merge). Writes round winners to outv/outi (thread 0), returns pred.
// Tiebreak: lower index wins. Ends with __syncthreads (outv visible).
__device__ __forceinline__ float block_extract_rounds(
    float (&tv)[K_TOP], int (&ti)[K_TOP], const int tid, float* sv, int* si,
    float* outv, int* outi) {
  const int lane = tid & 63;
  const int wid = tid >> 6;
  float pred = 0.0f;
#pragma unroll
  for (int k = 0; k < K_TOP; ++k) {
    float v = tv[0];
    int i = ti[0];
#pragma unroll
    for (int off = 32; off >= 1; off >>= 1) {
      const float ov = __shfl_xor(v, off, 64);
      const int oi = __shfl_xor(i, off, 64);
      if (ov > v || (ov == v && oi < i)) {
        v = ov;
        i = oi;
      }
    }
    if (lane == 0) {
      sv[wid] = v;
      si[wid] = i;
    }
    __syncthreads();
    float wv = sv[0];
    int wi = si[0];
#pragma unroll
    for (int w = 1; w < THREADS / 64; ++w) {
      const float ov = sv[w];
      const int oi = si[w];
      if (ov > wv || (ov == wv && oi < wi)) {
        wv = ov;
        wi = oi;
      }
    }
    if (tid == 0) {
      outv[k] = wv;
      outi[k] = wi;
    }
    __syncthreads();  // sv/si reusable next round; outv[k] visible at return

    pred += wv * ((float)wi * STEP_W + 1.0f);

    if (tv[0] == wv && ti[0] == wi) {  // unique owner pops (index is unique)
#pragma unroll
      for (int j = 0; j < K_TOP - 1; ++j) {
        tv[j] = tv[j + 1];
        ti[j] = ti[j + 1];
      }
      tv[K_TOP - 1] = -INFINITY;
      ti[K_TOP - 1] = 0x7FFFFFFF;
    }
  }
  return pred;
}

__global__ __launch_bounds__(THREADS) void topk_rows_kernel(
    const float* __restrict__ inp, const float* __restrict__ target,
    float* __restrict__ row_err) {
  __shared__ float bufv[CAP];
  __shared__ int bufi[CAP];
  __shared__ unsigned cnt;
  __shared__ float sv[THREADS / 64];
  __shared__ int si[THREADS / 64];

  const int row = blockIdx.x;
  const int tid = threadIdx.x;
  const float4* rp4 =
      reinterpret_cast<const float4*>(inp + (size_t)row * N_COLS);

  float tv[K_TOP];
  int ti[K_TOP];
#pragma unroll
  for (int j = 0; j < K_TOP; ++j) {
    tv[j] = -INFINITY;
    ti[j] = 0x7FFFFFFF;
  }

  if (tid == 0) cnt = K_TOP;  // slots 0..9 reserved for bootstrap winners

  // ---- bootstrap: exact top-10 of first 4096 elements (per-lane 16) ----
#pragma unroll
  for (int it = 0; it < BOOT_ITERS; ++it) {
    const int v4 = it * THREADS + tid;
    const float4 d = rp4[v4];
    const int c0 = v4 * 4;
    const float m = fmaxf(fmaxf(d.x, d.y), fmaxf(d.z, d.w));
    if (m > tv[K_TOP - 1]) {
      TRY_INSERT(d.x, c0 + 0);
      TRY_INSERT(d.y, c0 + 1);
      TRY_INSERT(d.z, c0 + 2);
      TRY_INSERT(d.w, c0 + 3);
    }
  }
  __syncthreads();  // cnt init visible before extraction rounds
  (void)block_extract_rounds(tv, ti, tid, sv, si, bufv, bufi);
  const float T = bufv[K_TOP - 1];  // exact 10th largest of prefix:
                                    // valid lower bound on row's 10th largest

  // ---- stream remaining 28672 elements: cheap filter, rare LDS push ----
#pragma unroll 4
  for (int it = BOOT_ITERS; it < TOTAL_ITERS; ++it) {
    const int v4 = it * THREADS + tid;
    const float4 d = rp4[v4];
    const int c0 = v4 * 4;
    const float m = fmaxf(fmaxf(d.x, d.y), fmaxf(d.z, d.w));
    if (m >= T) {  // >= : keep boundary ties (lower-index entry already kept)
      if (d.x >= T) {
        const unsigned p = atomicAdd(&cnt, 1u);
        if (p < CAP) { bufv[p] = d.x; bufi[p] = c0 + 0; }
      }
      if (d.y >= T) {
        const unsigned p = atomicAdd(&cnt, 1u);
        if (p < CAP) { bufv[p] = d.y; bufi[p] = c0 + 1; }
      }
      if (d.z >= T) {
        const unsigned p = atomicAdd(&cnt, 1u);
        if (p < CAP) { bufv[p] = d.z; bufi[p] = c0 + 2; }
      }
      if (d.w >= T) {
        const unsigned p = atomicAdd(&cnt, 1u);
        if (p < CAP) { bufv[p] = d.w; bufi[p] = c0 + 3; }
      }
    }
  }
  __syncthreads();
  const unsigned total = cnt;  // deterministic (set of survivors is data-only)

  float pred;
  if (total <= CAP) {
    // ---- select top-10 of candidates (10 bootstrap + survivors) ----
#pragma unroll
    for (int j = 0; j < K_TOP; ++j) {
      tv[j] = -INFINITY;
      ti[j] = 0x7FFFFFFF;
    }
    for (unsigned p = tid; p < total; p += THREADS) {
      const float v = bufv[p];
      const int i = bufi[p];
      TRY_INSERT_TB(v, i);
    }
    __syncthreads();
    pred = block_extract_rounds(tv, ti, tid, sv, si, bufv, bufi);
  } else {
    // ---- overflow fallback (never for N(0,1) data): exact full rescan ----
#pragma unroll
    for (int j = 0; j < K_TOP; ++j) {
      tv[j] = -INFINITY;
      ti[j] = 0x7FFFFFFF;
    }
    for (int it = 0; it < TOTAL_ITERS; ++it) {
      const int v4 = it * THREADS + tid;
      const float4 d = rp4[v4];
      const int c0 = v4 * 4;
      const float m = fmaxf(fmaxf(d.x, d.y), fmaxf(d.z, d.w));
      if (m > tv[K_TOP - 1]) {
        TRY_INSERT(d.x, c0 + 0);
        TRY_INSERT(d.y, c0 + 1);
        TRY_INSERT(d.z, c0 + 2);
        TRY_INSERT(d.w, c0 + 3);
      }
    }
    __syncthreads();
    pred = block_extract_rounds(tv, ti, tid, sv, si, bufv, bufi);
  }

  if (tid == 0) {
    const float e = target[row] - pred;
    row_err[row] = e * e;
  }
}

__global__ __launch_bounds__(THREADS) void reduce_mean_kernel(
    const float* __restrict__ row_err, float* __restrict__ out) {
  const int tid = threadIdx.x;
  float s = 0.0f;
#pragma unroll
  for (int i = tid; i < N_ROWS; i += THREADS) s += row_err[i];
#pragma unroll
  for (int off = 32; off >= 1; off >>= 1) s += __shfl_xor(s, off, 64);
  __shared__ float sw[THREADS / 64];
  const int lane = tid & 63;
  const int wid = tid >> 6;
  if (lane == 0) sw[wid] = s;
  __syncthreads();
  if (tid == 0) {
    float t = 0.0f;
#pragma unroll
    for (int w = 0; w < THREADS / 64; ++w) t += sw[w];
    out[0] = t / (float)N_ROWS;
  }
}

extern "C" void kernel_launch(void* const* d_in, const int* in_sizes, int n_in,
                              void* d_out, int out_size, void* d_ws,
                              size_t ws_size, hipStream_t stream) {
  const float* inp = (const float*)d_in[0];     // [8192, 32768] f32
  const float* target = (const float*)d_in[1];  // [8192] f32
  float* row_err = (float*)d_ws;                // 8192 f32 scratch
  float* out = (float*)d_out;                   // scalar f32

  topk_rows_kernel<<<N_ROWS, THREADS, 0, stream>>>(inp, target, row_err);
  reduce_mean_kernel<<<1, THREADS, 0, stream>>>(row_err, out);
}

// Round 3
// 226.597 us; speedup vs baseline: 1.5240x; 1.2140x over previous
//
#include <hip/hip_runtime.h>
#include <math.h>

#define N_ROWS 8192
#define N_COLS 32768
#define K_TOP 10
#define STEP_W 0.1f
#define THREADS 256
#define CAP 512      // candidate slots per row (E[surv]=203, sigma=14 @ T0=2.5)
#define T0 2.5f      // fixed filter threshold; fallback handles degenerate data
#define ITERS1 (N_COLS / 4 / THREADS)  // 32

// Insert (v,i) into descending sorted register lists tv/ti. Strict '>' :
// valid when each lane visits strictly increasing column indices.
#define TRY_INSERT(v, i)                                                      \
  do {                                                                        \
    if ((v) > tv[K_TOP - 1]) {                                                \
      tv[K_TOP - 1] = (v);                                                    \
      ti[K_TOP - 1] = (i);                                                    \
      _Pragma("unroll") for (int _j = K_TOP - 1; _j >= 1; --_j) {             \
        if (tv[_j] > tv[_j - 1]) {                                            \
          float _tv = tv[_j]; tv[_j] = tv[_j - 1]; tv[_j - 1] = _tv;          \
          int   _ti = ti[_j]; ti[_j] = ti[_j - 1]; ti[_j - 1] = _ti;          \
        }                                                                     \
      }                                                                       \
    }                                                                         \
  } while (0)

// Order-insensitive insert: total order (value desc, index asc) — safe for
// candidates arriving in arbitrary (atomic-append) order.
#define TRY_INSERT_TB(v, i)                                                   \
  do {                                                                        \
    if ((v) > tv[K_TOP - 1] ||                                                \
        ((v) == tv[K_TOP - 1] && (i) < ti[K_TOP - 1])) {                      \
      tv[K_TOP - 1] = (v);                                                    \
      ti[K_TOP - 1] = (i);                                                    \
      _Pragma("unroll") for (int _j = K_TOP - 1; _j >= 1; --_j) {             \
        if (tv[_j] > tv[_j - 1] ||                                            \
            (tv[_j] == tv[_j - 1] && ti[_j] < ti[_j - 1])) {                  \
          float _tv = tv[_j]; tv[_j] = tv[_j - 1]; tv[_j - 1] = _tv;          \
          int   _ti = ti[_j]; ti[_j] = ti[_j - 1]; ti[_j - 1] = _ti;          \
        }                                                                     \
      }                                                                       \
    }                                                                         \
  } while (0)

// ---------- pass 1: pure streaming threshold filter (HBM-bound) ----------
__global__ __launch_bounds__(THREADS) void filter_kernel(
    const float* __restrict__ inp, float* __restrict__ cand_v,
    int* __restrict__ cand_i, unsigned* __restrict__ cand_cnt) {
  __shared__ float lv[CAP];
  __shared__ int li[CAP];
  __shared__ unsigned cnt;

  const int row = blockIdx.x;
  const int tid = threadIdx.x;
  if (tid == 0) cnt = 0;
  __syncthreads();

  const float4* rp4 =
      reinterpret_cast<const float4*>(inp + (size_t)row * N_COLS);
#pragma unroll 4
  for (int it = 0; it < ITERS1; ++it) {
    const int v4 = it * THREADS + tid;
    const float4 d = rp4[v4];
    const int c0 = v4 * 4;
    const float m = fmaxf(fmaxf(d.x, d.y), fmaxf(d.z, d.w));
    if (m >= T0) {
      if (d.x >= T0) {
        const unsigned p = atomicAdd(&cnt, 1u);
        if (p < CAP) { lv[p] = d.x; li[p] = c0 + 0; }
      }
      if (d.y >= T0) {
        const unsigned p = atomicAdd(&cnt, 1u);
        if (p < CAP) { lv[p] = d.y; li[p] = c0 + 1; }
      }
      if (d.z >= T0) {
        const unsigned p = atomicAdd(&cnt, 1u);
        if (p < CAP) { lv[p] = d.z; li[p] = c0 + 2; }
      }
      if (d.w >= T0) {
        const unsigned p = atomicAdd(&cnt, 1u);
        if (p < CAP) { lv[p] = d.w; li[p] = c0 + 3; }
      }
    }
  }
  __syncthreads();

  const unsigned total = cnt;
  const unsigned stored = total < CAP ? total : CAP;
  float* dv = cand_v + (size_t)row * CAP;
  int* di = cand_i + (size_t)row * CAP;
  for (unsigned p = tid; p < stored; p += THREADS) {
    dv[p] = lv[p];
    di[p] = li[p];
  }
  if (tid == 0) cand_cnt[row] = total;  // full count: >CAP triggers fallback
}

// ---------- pass 2: one wave per row, top-10 of candidates ----------
__global__ __launch_bounds__(THREADS) void select_kernel(
    const float* __restrict__ inp, const float* __restrict__ target,
    const float* __restrict__ cand_v, const int* __restrict__ cand_i,
    const unsigned* __restrict__ cand_cnt, float* __restrict__ row_err) {
  const int tid = threadIdx.x;
  const int lane = tid & 63;
  const int wid = tid >> 6;
  const int row = blockIdx.x * (THREADS / 64) + wid;

  float tv[K_TOP];
  int ti[K_TOP];
#pragma unroll
  for (int j = 0; j < K_TOP; ++j) {
    tv[j] = -INFINITY;
    ti[j] = 0x7FFFFFFF;
  }

  const unsigned total = cand_cnt[row];
  if (total >= K_TOP && total <= CAP) {
    const float* dv = cand_v + (size_t)row * CAP;
    const int* di = cand_i + (size_t)row * CAP;
    for (unsigned p = lane; p < total; p += 64) {
      const float v = dv[p];
      const int i = di[p];
      TRY_INSERT_TB(v, i);
    }
  } else {
    // degenerate-data fallback: exact rescan of the row (never taken for
    // N(0,1) inputs; keeps correctness + determinism for anything else)
    const float4* rp4 =
        reinterpret_cast<const float4*>(inp + (size_t)row * N_COLS);
    for (int it = 0; it < N_COLS / 4 / 64; ++it) {
      const int v4 = it * 64 + lane;  // per-lane strictly increasing indices
      const float4 d = rp4[v4];
      const int c0 = v4 * 4;
      const float m = fmaxf(fmaxf(d.x, d.y), fmaxf(d.z, d.w));
      if (m > tv[K_TOP - 1]) {
        TRY_INSERT(d.x, c0 + 0);
        TRY_INSERT(d.y, c0 + 1);
        TRY_INSERT(d.z, c0 + 2);
        TRY_INSERT(d.w, c0 + 3);
      }
    }
  }

  // wave-local 10-round extraction (argmax with lower-index tiebreak)
  float pred = 0.0f;
#pragma unroll
  for (int k = 0; k < K_TOP; ++k) {
    float v = tv[0];
    int i = ti[0];
#pragma unroll
    for (int off = 32; off >= 1; off >>= 1) {
      const float ov = __shfl_xor(v, off, 64);
      const int oi = __shfl_xor(i, off, 64);
      if (ov > v || (ov == v && oi < i)) {
        v = ov;
        i = oi;
      }
    }
    pred += v * ((float)i * STEP_W + 1.0f);
    if (tv[0] == v && ti[0] == i) {  // unique owner (indices unique) pops
#pragma unroll
      for (int j = 0; j < K_TOP - 1; ++j) {
        tv[j] = tv[j + 1];
        ti[j] = ti[j + 1];
      }
      tv[K_TOP - 1] = -INFINITY;
      ti[K_TOP - 1] = 0x7FFFFFFF;
    }
  }

  if (lane == 0) {
    const float e = target[row] - pred;
    row_err[row] = e * e;
  }
}

// ---------- pass 3: deterministic mean over 8192 row errors ----------
__global__ __launch_bounds__(THREADS) void reduce_mean_kernel(
    const float* __restrict__ row_err, float* __restrict__ out) {
  const int tid = threadIdx.x;
  float s = 0.0f;
#pragma unroll
  for (int i = tid; i < N_ROWS; i += THREADS) s += row_err[i];
#pragma unroll
  for (int off = 32; off >= 1; off >>= 1) s += __shfl_xor(s, off, 64);
  __shared__ float sw[THREADS / 64];
  const int lane = tid & 63;
  const int wid = tid >> 6;
  if (lane == 0) sw[wid] = s;
  __syncthreads();
  if (tid == 0) {
    float t = 0.0f;
#pragma unroll
    for (int w = 0; w < THREADS / 64; ++w) t += sw[w];
    out[0] = t / (float)N_ROWS;
  }
}

extern "C" void kernel_launch(void* const* d_in, const int* in_sizes, int n_in,
                              void* d_out, int out_size, void* d_ws,
                              size_t ws_size, hipStream_t stream) {
  const float* inp = (const float*)d_in[0];     // [8192, 32768] f32
  const float* target = (const float*)d_in[1];  // [8192] f32
  float* out = (float*)d_out;                   // scalar f32

  // ws layout: row_err (32KB) | cand_cnt (32KB) | cand_v (16MB) | cand_i (16MB)
  char* ws = (char*)d_ws;
  float* row_err = (float*)ws;
  unsigned* cand_cnt = (unsigned*)(ws + 32 * 1024);
  float* cand_v = (float*)(ws + 64 * 1024);
  int* cand_i = (int*)(ws + 64 * 1024 + (size_t)N_ROWS * CAP * 4);

  filter_kernel<<<N_ROWS, THREADS, 0, stream>>>(inp, cand_v, cand_i, cand_cnt);
  select_kernel<<<N_ROWS / (THREADS / 64), THREADS, 0, stream>>>(
      inp, target, cand_v, cand_i, cand_cnt, row_err);
  reduce_mean_kernel<<<1, THREADS, 0, stream>>>(row_err, out);
}

// Round 5
// 195.213 us; speedup vs baseline: 1.7690x; 1.1608x over previous
//
#include <hip/hip_runtime.h>
#include <math.h>

#define N_ROWS 8192
#define N_COLS 32768
#define K_TOP 10
#define STEP_W 0.1f
#define THREADS 256
#define CAP 512      // candidate slots/row (E=44.2, sigma=6.6 @ T0=3.0)
#define T0 3.0f      // fixed filter threshold; fallback handles anything else
#define QPT 32       // float4 quads per thread (32768/4/256)
#define BATCH 8      // loads kept in flight per thread
#define OUTER (QPT / BATCH)  // 4

typedef float f4 __attribute__((ext_vector_type(4)));  // native vector: ok for
                                                       // __builtin_nontemporal_load

// Insert (v,i) into descending sorted register lists tv/ti. Strict '>' :
// valid when each lane visits strictly increasing column indices.
#define TRY_INSERT(v, i)                                                      \
  do {                                                                        \
    if ((v) > tv[K_TOP - 1]) {                                                \
      tv[K_TOP - 1] = (v);                                                    \
      ti[K_TOP - 1] = (i);                                                    \
      _Pragma("unroll") for (int _j = K_TOP - 1; _j >= 1; --_j) {             \
        if (tv[_j] > tv[_j - 1]) {                                            \
          float _tv = tv[_j]; tv[_j] = tv[_j - 1]; tv[_j - 1] = _tv;          \
          int   _ti = ti[_j]; ti[_j] = ti[_j - 1]; ti[_j - 1] = _ti;          \
        }                                                                     \
      }                                                                       \
    }                                                                         \
  } while (0)

// Order-insensitive insert: total order (value desc, index asc) — safe for
// candidates arriving in arbitrary (atomic-append) order.
#define TRY_INSERT_TB(v, i)                                                   \
  do {                                                                        \
    if ((v) > tv[K_TOP - 1] ||                                                \
        ((v) == tv[K_TOP - 1] && (i) < ti[K_TOP - 1])) {                      \
      tv[K_TOP - 1] = (v);                                                    \
      ti[K_TOP - 1] = (i);                                                    \
      _Pragma("unroll") for (int _j = K_TOP - 1; _j >= 1; --_j) {             \
        if (tv[_j] > tv[_j - 1] ||                                            \
            (tv[_j] == tv[_j - 1] && ti[_j] < ti[_j - 1])) {                  \
          float _tv = tv[_j]; tv[_j] = tv[_j - 1]; tv[_j - 1] = _tv;          \
          int   _ti = ti[_j]; ti[_j] = ti[_j - 1]; ti[_j - 1] = _ti;          \
        }                                                                     \
      }                                                                       \
    }                                                                         \
  } while (0)

// ---------- pass 1: pure streaming threshold filter (HBM-bound) ----------
__global__ __launch_bounds__(THREADS) void filter_kernel(
    const float* __restrict__ inp, float* __restrict__ cand_v,
    int* __restrict__ cand_i, unsigned* __restrict__ cand_cnt) {
  __shared__ float lv[CAP];
  __shared__ int li[CAP];
  __shared__ unsigned cnt;

  const int row = blockIdx.x;
  const int tid = threadIdx.x;
  if (tid == 0) cnt = 0;
  __syncthreads();

  const f4* rp4 = reinterpret_cast<const f4*>(inp + (size_t)row * N_COLS);

  for (int it = 0; it < OUTER; ++it) {
    // issue BATCH loads back-to-back (static indices only: fully unrolled)
    f4 d[BATCH];
#pragma unroll
    for (int j = 0; j < BATCH; ++j)
      d[j] = __builtin_nontemporal_load(&rp4[(it * BATCH + j) * THREADS + tid]);
#pragma unroll
    for (int j = 0; j < BATCH; ++j) {
      const int c0 = ((it * BATCH + j) * THREADS + tid) * 4;
      const float m = fmaxf(fmaxf(d[j][0], d[j][1]), fmaxf(d[j][2], d[j][3]));
      if (m >= T0) {  // rare at wave level (~29% of wave-iterations)
        if (d[j][0] >= T0) {
          const unsigned p = atomicAdd(&cnt, 1u);
          if (p < CAP) { lv[p] = d[j][0]; li[p] = c0 + 0; }
        }
        if (d[j][1] >= T0) {
          const unsigned p = atomicAdd(&cnt, 1u);
          if (p < CAP) { lv[p] = d[j][1]; li[p] = c0 + 1; }
        }
        if (d[j][2] >= T0) {
          const unsigned p = atomicAdd(&cnt, 1u);
          if (p < CAP) { lv[p] = d[j][2]; li[p] = c0 + 2; }
        }
        if (d[j][3] >= T0) {
          const unsigned p = atomicAdd(&cnt, 1u);
          if (p < CAP) { lv[p] = d[j][3]; li[p] = c0 + 3; }
        }
      }
    }
  }
  __syncthreads();

  const unsigned total = cnt;
  const unsigned stored = total < CAP ? total : CAP;
  float* dv = cand_v + (size_t)row * CAP;
  int* di = cand_i + (size_t)row * CAP;
  for (unsigned p = tid; p < stored; p += THREADS) {
    dv[p] = lv[p];
    di[p] = li[p];
  }
  if (tid == 0) cand_cnt[row] = total;  // full count: >CAP triggers fallback
}

// ---------- pass 2: one wave per row, top-10 of candidates ----------
__global__ __launch_bounds__(THREADS) void select_kernel(
    const float* __restrict__ inp, const float* __restrict__ target,
    const float* __restrict__ cand_v, const int* __restrict__ cand_i,
    const unsigned* __restrict__ cand_cnt, float* __restrict__ row_err) {
  const int tid = threadIdx.x;
  const int lane = tid & 63;
  const int wid = tid >> 6;
  const int row = blockIdx.x * (THREADS / 64) + wid;

  float tv[K_TOP];
  int ti[K_TOP];
#pragma unroll
  for (int j = 0; j < K_TOP; ++j) {
    tv[j] = -INFINITY;
    ti[j] = 0x7FFFFFFF;
  }

  const unsigned total = cand_cnt[row];
  if (total >= K_TOP && total <= CAP) {
    const float* dv = cand_v + (size_t)row * CAP;
    const int* di = cand_i + (size_t)row * CAP;
    for (unsigned p = lane; p < total; p += 64) {
      const float v = dv[p];
      const int i = di[p];
      TRY_INSERT_TB(v, i);
    }
  } else {
    // degenerate-data fallback: exact rescan of the row (never taken for
    // N(0,1) inputs; keeps correctness + determinism for anything else)
    const float4* rp4 =
        reinterpret_cast<const float4*>(inp + (size_t)row * N_COLS);
#pragma unroll 8
    for (int it = 0; it < N_COLS / 4 / 64; ++it) {
      const int v4 = it * 64 + lane;  // per-lane strictly increasing indices
      const float4 d = rp4[v4];
      const int c0 = v4 * 4;
      const float m = fmaxf(fmaxf(d.x, d.y), fmaxf(d.z, d.w));
      if (m > tv[K_TOP - 1]) {
        TRY_INSERT(d.x, c0 + 0);
        TRY_INSERT(d.y, c0 + 1);
        TRY_INSERT(d.z, c0 + 2);
        TRY_INSERT(d.w, c0 + 3);
      }
    }
  }

  // wave-local 10-round extraction (argmax with lower-index tiebreak)
  float pred = 0.0f;
#pragma unroll
  for (int k = 0; k < K_TOP; ++k) {
    float v = tv[0];
    int i = ti[0];
#pragma unroll
    for (int off = 32; off >= 1; off >>= 1) {
      const float ov = __shfl_xor(v, off, 64);
      const int oi = __shfl_xor(i, off, 64);
      if (ov > v || (ov == v && oi < i)) {
        v = ov;
        i = oi;
      }
    }
    pred += v * ((float)i * STEP_W + 1.0f);
    if (tv[0] == v && ti[0] == i) {  // unique owner (indices unique) pops
#pragma unroll
      for (int j = 0; j < K_TOP - 1; ++j) {
        tv[j] = tv[j + 1];
        ti[j] = ti[j + 1];
      }
      tv[K_TOP - 1] = -INFINITY;
      ti[K_TOP - 1] = 0x7FFFFFFF;
    }
  }

  if (lane == 0) {
    const float e = target[row] - pred;
    row_err[row] = e * e;
  }
}

// ---------- pass 3: deterministic mean over 8192 row errors ----------
__global__ __launch_bounds__(THREADS) void reduce_mean_kernel(
    const float* __restrict__ row_err, float* __restrict__ out) {
  const int tid = threadIdx.x;
  float s = 0.0f;
#pragma unroll
  for (int i = tid; i < N_ROWS; i += THREADS) s += row_err[i];
#pragma unroll
  for (int off = 32; off >= 1; off >>= 1) s += __shfl_xor(s, off, 64);
  __shared__ float sw[THREADS / 64];
  const int lane = tid & 63;
  const int wid = tid >> 6;
  if (lane == 0) sw[wid] = s;
  __syncthreads();
  if (tid == 0) {
    float t = 0.0f;
#pragma unroll
    for (int w = 0; w < THREADS / 64; ++w) t += sw[w];
    out[0] = t / (float)N_ROWS;
  }
}

extern "C" void kernel_launch(void* const* d_in, const int* in_sizes, int n_in,
                              void* d_out, int out_size, void* d_ws,
                              size_t ws_size, hipStream_t stream) {
  const float* inp = (const float*)d_in[0];     // [8192, 32768] f32
  const float* target = (const float*)d_in[1];  // [8192] f32
  float* out = (float*)d_out;                   // scalar f32

  // ws layout: row_err (32KB) | cand_cnt (32KB) | cand_v (16MB) | cand_i (16MB)
  char* ws = (char*)d_ws;
  float* row_err = (float*)ws;
  unsigned* cand_cnt = (unsigned*)(ws + 32 * 1024);
  float* cand_v = (float*)(ws + 64 * 1024);
  int* cand_i = (int*)(ws + 64 * 1024 + (size_t)N_ROWS * CAP * 4);

  filter_kernel<<<N_ROWS, THREADS, 0, stream>>>(inp, cand_v, cand_i, cand_cnt);
  select_kernel<<<N_ROWS / (THREADS / 64), THREADS, 0, stream>>>(
      inp, target, cand_v, cand_i, cand_cnt, row_err);
  reduce_mean_kernel<<<1, THREADS, 0, stream>>>(row_err, out);
}

// Round 6
// 174.071 us; speedup vs baseline: 1.9839x; 1.1215x over previous
//
#include <hip/hip_runtime.h>
#include <math.h>

#define N_ROWS 8192
#define N_COLS 32768
#define K_TOP 10
#define STEP_W 0.1f
#define THREADS 256
#define CAP 512      // candidate slots/row (E=44.2, sigma=6.6 @ T0=3.0)
#define T0 3.0f      // fixed filter threshold; fallback handles anything else
#define QPT 32       // float4 quads per thread (32768/4/256)
#define BATCH 8      // loads kept in flight per thread
#define OUTER (QPT / BATCH)  // 4

typedef float f4 __attribute__((ext_vector_type(4)));  // native vector: ok for
                                                       // __builtin_nontemporal_load

// Insert (v,i) into descending sorted register lists tv/ti. Strict '>' :
// valid when each lane visits strictly increasing column indices.
#define TRY_INSERT(v, i)                                                      \
  do {                                                                        \
    if ((v) > tv[K_TOP - 1]) {                                                \
      tv[K_TOP - 1] = (v);                                                    \
      ti[K_TOP - 1] = (i);                                                    \
      _Pragma("unroll") for (int _j = K_TOP - 1; _j >= 1; --_j) {             \
        if (tv[_j] > tv[_j - 1]) {                                            \
          float _tv = tv[_j]; tv[_j] = tv[_j - 1]; tv[_j - 1] = _tv;          \
          int   _ti = ti[_j]; ti[_j] = ti[_j - 1]; ti[_j - 1] = _ti;          \
        }                                                                     \
      }                                                                       \
    }                                                                         \
  } while (0)

// Order-insensitive insert: total order (value desc, index asc) — safe for
// candidates arriving in arbitrary (atomic-append) order.
#define TRY_INSERT_TB(v, i)                                                   \
  do {                                                                        \
    if ((v) > tv[K_TOP - 1] ||                                                \
        ((v) == tv[K_TOP - 1] && (i) < ti[K_TOP - 1])) {                      \
      tv[K_TOP - 1] = (v);                                                    \
      ti[K_TOP - 1] = (i);                                                    \
      _Pragma("unroll") for (int _j = K_TOP - 1; _j >= 1; --_j) {             \
        if (tv[_j] > tv[_j - 1] ||                                            \
            (tv[_j] == tv[_j - 1] && ti[_j] < ti[_j - 1])) {                  \
          float _tv = tv[_j]; tv[_j] = tv[_j - 1]; tv[_j - 1] = _tv;          \
          int   _ti = ti[_j]; ti[_j] = ti[_j - 1]; ti[_j - 1] = _ti;          \
        }                                                                     \
      }                                                                       \
    }                                                                         \
  } while (0)

// Wave-local 10-round extraction over per-lane sorted lists. Returns pred.
// Tiebreak (value desc, index asc). No barriers — single wave only.
__device__ __forceinline__ float wave_extract(float (&tv)[K_TOP],
                                              int (&ti)[K_TOP]) {
  float pred = 0.0f;
#pragma unroll
  for (int k = 0; k < K_TOP; ++k) {
    float v = tv[0];
    int i = ti[0];
#pragma unroll
    for (int off = 32; off >= 1; off >>= 1) {
      const float ov = __shfl_xor(v, off, 64);
      const int oi = __shfl_xor(i, off, 64);
      if (ov > v || (ov == v && oi < i)) {
        v = ov;
        i = oi;
      }
    }
    pred += v * ((float)i * STEP_W + 1.0f);
    if (tv[0] == v && ti[0] == i) {  // unique owner (indices unique) pops
#pragma unroll
      for (int j = 0; j < K_TOP - 1; ++j) {
        tv[j] = tv[j + 1];
        ti[j] = ti[j + 1];
      }
      tv[K_TOP - 1] = -INFINITY;
      ti[K_TOP - 1] = 0x7FFFFFFF;
    }
  }
  return pred;
}

// ---------- pass 1 (fused): stream-filter + in-block top-10 select ----------
__global__ __launch_bounds__(THREADS) void fused_topk_kernel(
    const float* __restrict__ inp, const float* __restrict__ target,
    float* __restrict__ row_err) {
  __shared__ float lv[CAP];
  __shared__ int li[CAP];
  __shared__ unsigned cnt;
  __shared__ float sv[THREADS / 64];
  __shared__ int si[THREADS / 64];

  const int row = blockIdx.x;
  const int tid = threadIdx.x;
  const int lane = tid & 63;
  const int wid = tid >> 6;
  if (tid == 0) cnt = 0;
  __syncthreads();

  const f4* rp4 = reinterpret_cast<const f4*>(inp + (size_t)row * N_COLS);

  for (int it = 0; it < OUTER; ++it) {
    // issue BATCH loads back-to-back (static indices only: fully unrolled)
    f4 d[BATCH];
#pragma unroll
    for (int j = 0; j < BATCH; ++j)
      d[j] = __builtin_nontemporal_load(&rp4[(it * BATCH + j) * THREADS + tid]);
#pragma unroll
    for (int j = 0; j < BATCH; ++j) {
      const int c0 = ((it * BATCH + j) * THREADS + tid) * 4;
      const float m = fmaxf(fmaxf(d[j][0], d[j][1]), fmaxf(d[j][2], d[j][3]));
      if (m >= T0) {  // rare at wave level (~29% of wave-iterations)
        if (d[j][0] >= T0) {
          const unsigned p = atomicAdd(&cnt, 1u);
          if (p < CAP) { lv[p] = d[j][0]; li[p] = c0 + 0; }
        }
        if (d[j][1] >= T0) {
          const unsigned p = atomicAdd(&cnt, 1u);
          if (p < CAP) { lv[p] = d[j][1]; li[p] = c0 + 1; }
        }
        if (d[j][2] >= T0) {
          const unsigned p = atomicAdd(&cnt, 1u);
          if (p < CAP) { lv[p] = d[j][2]; li[p] = c0 + 2; }
        }
        if (d[j][3] >= T0) {
          const unsigned p = atomicAdd(&cnt, 1u);
          if (p < CAP) { lv[p] = d[j][3]; li[p] = c0 + 3; }
        }
      }
    }
  }
  __syncthreads();
  const unsigned total = cnt;  // block-uniform: branch below is barrier-safe

  if (total >= K_TOP && total <= CAP) {
    // common path: wave 0 alone selects top-10 of ~44 LDS candidates
    if (wid == 0) {
      float tv[K_TOP];
      int ti[K_TOP];
#pragma unroll
      for (int j = 0; j < K_TOP; ++j) {
        tv[j] = -INFINITY;
        ti[j] = 0x7FFFFFFF;
      }
      for (unsigned p = lane; p < total; p += 64) {
        const float v = lv[p];
        const int i = li[p];
        TRY_INSERT_TB(v, i);
      }
      const float pred = wave_extract(tv, ti);
      if (lane == 0) {
        const float e = target[row] - pred;
        row_err[row] = e * e;
      }
    }
  } else {
    // degenerate-data fallback: exact whole-block rescan (never for N(0,1))
    float tv[K_TOP];
    int ti[K_TOP];
#pragma unroll
    for (int j = 0; j < K_TOP; ++j) {
      tv[j] = -INFINITY;
      ti[j] = 0x7FFFFFFF;
    }
#pragma unroll 4
    for (int it = 0; it < QPT; ++it) {
      const int v4 = it * THREADS + tid;  // per-lane strictly increasing cols
      const f4 d = rp4[v4];
      const int c0 = v4 * 4;
      const float m = fmaxf(fmaxf(d[0], d[1]), fmaxf(d[2], d[3]));
      if (m > tv[K_TOP - 1]) {
        TRY_INSERT(d[0], c0 + 0);
        TRY_INSERT(d[1], c0 + 1);
        TRY_INSERT(d[2], c0 + 2);
        TRY_INSERT(d[3], c0 + 3);
      }
    }
    // block-level 10-round extraction (wave argmax + cross-wave LDS combine)
    float pred = 0.0f;
#pragma unroll
    for (int k = 0; k < K_TOP; ++k) {
      float v = tv[0];
      int i = ti[0];
#pragma unroll
      for (int off = 32; off >= 1; off >>= 1) {
        const float ov = __shfl_xor(v, off, 64);
        const int oi = __shfl_xor(i, off, 64);
        if (ov > v || (ov == v && oi < i)) {
          v = ov;
          i = oi;
        }
      }
      if (lane == 0) {
        sv[wid] = v;
        si[wid] = i;
      }
      __syncthreads();
      float wv = sv[0];
      int wi = si[0];
#pragma unroll
      for (int w = 1; w < THREADS / 64; ++w) {
        const float ov = sv[w];
        const int oi = si[w];
        if (ov > wv || (ov == wv && oi < wi)) {
          wv = ov;
          wi = oi;
        }
      }
      __syncthreads();
      pred += wv * ((float)wi * STEP_W + 1.0f);
      if (tv[0] == wv && ti[0] == wi) {
#pragma unroll
        for (int j = 0; j < K_TOP - 1; ++j) {
          tv[j] = tv[j + 1];
          ti[j] = ti[j + 1];
        }
        tv[K_TOP - 1] = -INFINITY;
        ti[K_TOP - 1] = 0x7FFFFFFF;
      }
    }
    if (tid == 0) {
      const float e = target[row] - pred;
      row_err[row] = e * e;
    }
  }
}

// ---------- pass 2: deterministic mean over 8192 row errors ----------
__global__ __launch_bounds__(THREADS) void reduce_mean_kernel(
    const float* __restrict__ row_err, float* __restrict__ out) {
  const int tid = threadIdx.x;
  float s = 0.0f;
#pragma unroll
  for (int i = tid; i < N_ROWS; i += THREADS) s += row_err[i];
#pragma unroll
  for (int off = 32; off >= 1; off >>= 1) s += __shfl_xor(s, off, 64);
  __shared__ float sw[THREADS / 64];
  const int lane = tid & 63;
  const int wid = tid >> 6;
  if (lane == 0) sw[wid] = s;
  __syncthreads();
  if (tid == 0) {
    float t = 0.0f;
#pragma unroll
    for (int w = 0; w < THREADS / 64; ++w) t += sw[w];
    out[0] = t / (float)N_ROWS;
  }
}

extern "C" void kernel_launch(void* const* d_in, const int* in_sizes, int n_in,
                              void* d_out, int out_size, void* d_ws,
                              size_t ws_size, hipStream_t stream) {
  const float* inp = (const float*)d_in[0];     // [8192, 32768] f32
  const float* target = (const float*)d_in[1];  // [8192] f32
  float* out = (float*)d_out;                   // scalar f32
  float* row_err = (float*)d_ws;                // 8192 f32 scratch

  fused_topk_kernel<<<N_ROWS, THREADS, 0, stream>>>(inp, target, row_err);
  reduce_mean_kernel<<<1, THREADS, 0, stream>>>(row_err, out);
}